// Round 7
// baseline (711.864 us; speedup 1.0000x reference)
//
#include <hip/hip_runtime.h>
#include <hip/hip_bf16.h>

#define BB 8
#define TT 1024
#define DD 1024
#define HH 16
#define DH 64

typedef __attribute__((ext_vector_type(8))) short short8;
typedef __attribute__((ext_vector_type(4))) float f32x4;

__device__ __forceinline__ unsigned short f2bf(float f) {
  unsigned int u = __builtin_bit_cast(unsigned int, f);
  unsigned int rounding = 0x7fffu + ((u >> 16) & 1u);
  u += rounding;
  return (unsigned short)(u >> 16);
}
__device__ __forceinline__ float bf2f(unsigned short u) {
  unsigned int x = ((unsigned int)u) << 16;
  return __builtin_bit_cast(float, x);
}

// ---- f32 -> bf16 TRANSPOSING convert: out[n][k] = bf16(in[k][n]), 1024x1024 ----
__global__ __launch_bounds__(256) void convertT_k(const float* __restrict__ in,
                                                  unsigned short* __restrict__ out) {
  int g = blockIdx.x * 256 + threadIdx.x;   // granule id: 1024 n x 128 k-groups
  int n = g & (DD - 1);
  int kb = (g >> 10) * 8;
  short8 o;
#pragma unroll
  for (int j = 0; j < 8; ++j)
    o[j] = (short)f2bf(in[(size_t)(kb + j) * DD + n]);
  *(short8*)(out + (size_t)n * DD + kb) = o;
}

// ---------------- bf16 MFMA GEMM: C = A @ W + bias ----------------
// A: MxK row-major (f32 if AF32 else bf16). Wt: NxK row-major bf16 (PRE-TRANSPOSED).
// C: MxN (f32 if OF32 else bf16). Tile 128x128, BK=32, 4 waves (2x2).
template<int AF32, int OF32>
__global__ __launch_bounds__(256) void gemm_k(const void* __restrict__ Ap,
                                              const unsigned short* __restrict__ Wt,
                                              const float* __restrict__ bias,
                                              void* __restrict__ Cp,
                                              int M, int N, int K) {
  __shared__ unsigned short As[128][40];  // [m][k] padded
  __shared__ unsigned short Bs[128][40];  // [n][k] padded
  const int tid = threadIdx.x;
  const int lane = tid & 63;
  const int w = tid >> 6;
  const int lo = lane & 15, hi = lane >> 4;
  const int wm = w >> 1, wn = w & 1;
  const int m0 = blockIdx.y * 128, n0 = blockIdx.x * 128;
  f32x4 acc[4][4] = {};
  for (int k0 = 0; k0 < K; k0 += 32) {
    // stage A tile (128m x 32k) -> bf16 LDS
#pragma unroll
    for (int it = 0; it < 2; ++it) {
      int c = tid + 256 * it;
      int r = c >> 2, cb = (c & 3) * 8;
      short8 sv;
      if constexpr (AF32) {
        const float* src = (const float*)Ap + (size_t)(m0 + r) * K + k0 + cb;
        float4 v0 = *(const float4*)src;
        float4 v1 = *(const float4*)(src + 4);
        sv[0] = (short)f2bf(v0.x); sv[1] = (short)f2bf(v0.y);
        sv[2] = (short)f2bf(v0.z); sv[3] = (short)f2bf(v0.w);
        sv[4] = (short)f2bf(v1.x); sv[5] = (short)f2bf(v1.y);
        sv[6] = (short)f2bf(v1.z); sv[7] = (short)f2bf(v1.w);
      } else {
        sv = *(const short8*)((const unsigned short*)Ap + (size_t)(m0 + r) * K + k0 + cb);
      }
      *(short8*)&As[r][cb] = sv;
    }
    // stage B tile (128n x 32k) from pre-transposed Wt: vector load + vector LDS write
#pragma unroll
    for (int it = 0; it < 2; ++it) {
      int c = tid + 256 * it;
      int nn = c >> 2, k8 = (c & 3) * 8;
      short8 v = *(const short8*)(Wt + (size_t)(n0 + nn) * K + k0 + k8);
      *(short8*)&Bs[nn][k8] = v;
    }
    __syncthreads();
    short8 af[4], bf[4];
#pragma unroll
    for (int mt = 0; mt < 4; ++mt) af[mt] = *(const short8*)&As[wm * 64 + mt * 16 + lo][hi * 8];
#pragma unroll
    for (int nt = 0; nt < 4; ++nt) bf[nt] = *(const short8*)&Bs[wn * 64 + nt * 16 + lo][hi * 8];
#pragma unroll
    for (int mt = 0; mt < 4; ++mt)
#pragma unroll
      for (int nt = 0; nt < 4; ++nt)
        acc[mt][nt] = __builtin_amdgcn_mfma_f32_16x16x32_bf16(af[mt], bf[nt], acc[mt][nt], 0, 0, 0);
    __syncthreads();
  }
#pragma unroll
  for (int mt = 0; mt < 4; ++mt) {
#pragma unroll
    for (int nt = 0; nt < 4; ++nt) {
      int col = n0 + wn * 64 + nt * 16 + lo;
      float bv = bias[col];
#pragma unroll
      for (int r = 0; r < 4; ++r) {
        int row = m0 + wm * 64 + mt * 16 + hi * 4 + r;
        float v = acc[mt][nt][r] + bv;
        if constexpr (OF32) ((float*)Cp)[(size_t)row * N + col] = v;
        else ((unsigned short*)Cp)[(size_t)row * N + col] = f2bf(v);
      }
    }
  }
}

// ------------- V transpose per head: (B,T,H,DH) -> (B,H,DH,T) -------------
__global__ __launch_bounds__(256) void transpose_v_k(const unsigned short* __restrict__ Vp,
                                                     unsigned short* __restrict__ Vt) {
  __shared__ unsigned short tile[64][72];
  const int blk = blockIdx.x;              // b*256 + h*16 + t-tile
  const int t0 = (blk & 15) * 64;
  const int h = (blk >> 4) & 15;
  const int b = blk >> 8;
  const int tid = threadIdx.x;
#pragma unroll
  for (int it = 0; it < 2; ++it) {
    int c = tid + 256 * it;
    int r = c >> 3, d8 = (c & 7) * 8;
    short8 v = *(const short8*)(Vp + ((size_t)(b * TT + t0 + r)) * DD + h * DH + d8);
    *(short8*)&tile[r][d8] = v;
  }
  __syncthreads();
#pragma unroll
  for (int it = 0; it < 2; ++it) {
    int c = tid + 256 * it;
    int d = c >> 3, t8 = (c & 7) * 8;
    short8 o;
#pragma unroll
    for (int j = 0; j < 8; ++j) o[j] = (short)tile[t8 + j][d];
    *(short8*)(Vt + ((size_t)(b * HH + h) * DH + d) * TT + t0 + t8) = o;
  }
}

// ---------------- flash attention (bias fused from raw spatial/edge/mask) ----------------
// block = 4 waves; wave w: 16 q-rows of one (b,h). KV-block = 32 keys.
// P is wave-private LDS -> NO __syncthreads needed (intra-wave DS ordering).
__global__ __launch_bounds__(256) void attn_k(const unsigned short* __restrict__ Qp,
                                              const unsigned short* __restrict__ Kp,
                                              const unsigned short* __restrict__ Vt,
                                              const float* __restrict__ spat,
                                              const float* __restrict__ edge,
                                              const int* __restrict__ mask,
                                              unsigned short* __restrict__ Obf) {
  __shared__ unsigned short P[4][16][40];
  const int blk = blockIdx.x;
  const int qt = blk & 15;
  const int h = (blk >> 4) & 15;
  const int b = blk >> 8;
  const int tid = threadIdx.x;
  const int w = tid >> 6;
  const int lane = tid & 63;
  const int lo = lane & 15, hi = lane >> 4;
  const int q0 = qt * 64 + w * 16;

  const unsigned short* Qb = Qp + ((size_t)b * TT + q0) * DD + h * DH;
  const unsigned short* Kb = Kp + ((size_t)b * TT) * DD + h * DH;
  const unsigned short* Vb = Vt + (size_t)(b * HH + h) * DH * TT;
  const float* Sp = spat + (size_t)b * TT * TT;
  const float* Ed = edge + (size_t)b * TT * TT;
  const int* Mk = mask + b * TT;

  short8 qf0 = *(const short8*)(Qb + (size_t)lo * DD + hi * 8);
  short8 qf1 = *(const short8*)(Qb + (size_t)lo * DD + 32 + hi * 8);

  float m[4], l[4];
  f32x4 acc[4] = {};
#pragma unroll
  for (int r = 0; r < 4; ++r) { m[r] = -INFINITY; l[r] = 0.f; }

  for (int k0 = 0; k0 < TT; k0 += 32) {
    short8 kf00, kf01, kf10, kf11;
    {
      const unsigned short* kp0 = Kb + (size_t)(k0 + lo) * DD + hi * 8;
      const unsigned short* kp1 = Kb + (size_t)(k0 + 16 + lo) * DD + hi * 8;
      kf00 = *(const short8*)kp0;  kf01 = *(const short8*)(kp0 + 32);
      kf10 = *(const short8*)kp1;  kf11 = *(const short8*)(kp1 + 32);
    }
    f32x4 sc0 = {}, sc1 = {};
    sc0 = __builtin_amdgcn_mfma_f32_16x16x32_bf16(qf0, kf00, sc0, 0, 0, 0);
    sc0 = __builtin_amdgcn_mfma_f32_16x16x32_bf16(qf1, kf01, sc0, 0, 0, 0);
    sc1 = __builtin_amdgcn_mfma_f32_16x16x32_bf16(qf0, kf10, sc1, 0, 0, 0);
    sc1 = __builtin_amdgcn_mfma_f32_16x16x32_bf16(qf1, kf11, sc1, 0, 0, 0);

    // masked bias, read directly from f32 spatial/edge (no reuse -> no precombine)
    const int mk0 = Mk[k0 + lo];
    const int mk1 = Mk[k0 + 16 + lo];

    float p0[4], p1[4], alpha[4];
#pragma unroll
    for (int r = 0; r < 4; ++r) {
      const size_t roff = (size_t)(q0 + hi * 4 + r) * TT + k0;
      const float* srow = Sp + roff;
      const float* erow = Ed + roff;
      float b0 = mk0 ? -1e30f : (srow[lo] + erow[lo]);
      float b1 = mk1 ? -1e30f : (srow[16 + lo] + erow[16 + lo]);
      float s0 = sc0[r] * 0.125f + b0;
      float s1 = sc1[r] * 0.125f + b1;
      float mx = fmaxf(s0, s1);
      mx = fmaxf(mx, __shfl_xor(mx, 1));
      mx = fmaxf(mx, __shfl_xor(mx, 2));
      mx = fmaxf(mx, __shfl_xor(mx, 4));
      mx = fmaxf(mx, __shfl_xor(mx, 8));
      float mn = fmaxf(m[r], mx);
      alpha[r] = __expf(m[r] - mn);
      m[r] = mn;
      p0[r] = __expf(s0 - mn);
      p1[r] = __expf(s1 - mn);
      float rs = p0[r] + p1[r];
      rs += __shfl_xor(rs, 1);
      rs += __shfl_xor(rs, 2);
      rs += __shfl_xor(rs, 4);
      rs += __shfl_xor(rs, 8);
      l[r] = l[r] * alpha[r] + rs;
    }
#pragma unroll
    for (int dt = 0; dt < 4; ++dt)
#pragma unroll
      for (int r = 0; r < 4; ++r) acc[dt][r] *= alpha[r];

#pragma unroll
    for (int r = 0; r < 4; ++r) {
      P[w][hi * 4 + r][lo] = f2bf(p0[r]);
      P[w][hi * 4 + r][lo + 16] = f2bf(p1[r]);
    }
    short8 pf = *(const short8*)&P[w][lo][hi * 8];
#pragma unroll
    for (int dt = 0; dt < 4; ++dt) {
      short8 vf = *(const short8*)(Vb + (size_t)(dt * 16 + lo) * TT + k0 + hi * 8);
      acc[dt] = __builtin_amdgcn_mfma_f32_16x16x32_bf16(pf, vf, acc[dt], 0, 0, 0);
    }
  }

  unsigned short* Ob = Obf + ((size_t)b * TT + q0) * DD + h * DH;
#pragma unroll
  for (int dt = 0; dt < 4; ++dt)
#pragma unroll
    for (int r = 0; r < 4; ++r) {
      float o = acc[dt][r] / l[r];
      Ob[(size_t)(hi * 4 + r) * DD + dt * 16 + lo] = f2bf(o);
    }
}

extern "C" void kernel_launch(void* const* d_in, const int* in_sizes, int n_in,
                              void* d_out, int out_size, void* d_ws, size_t ws_size,
                              hipStream_t stream) {
  const float* query = (const float*)d_in[0];
  const float* key   = (const float*)d_in[1];
  const float* value = (const float*)d_in[2];
  const float* spat  = (const float*)d_in[3];
  const float* edge  = (const float*)d_in[4];
  const int*   maskp = (const int*)d_in[5];
  const float* Wq = (const float*)d_in[6];  const float* bq = (const float*)d_in[7];
  const float* Wk = (const float*)d_in[8];  const float* bk = (const float*)d_in[9];
  const float* Wv = (const float*)d_in[10]; const float* bv = (const float*)d_in[11];
  const float* Wo = (const float*)d_in[12]; const float* bo = (const float*)d_in[13];
  float* out = (float*)d_out;

  unsigned short* WqT = (unsigned short*)d_ws;          // [n][k] bf16
  unsigned short* WkT = WqT + (size_t)DD * DD;
  unsigned short* WvT = WkT + (size_t)DD * DD;
  unsigned short* WoT = WvT + (size_t)DD * DD;
  unsigned short* Qp    = WoT + (size_t)DD * DD;
  unsigned short* Kp    = Qp + (size_t)BB * TT * DD;
  unsigned short* Vp    = Kp + (size_t)BB * TT * DD;
  unsigned short* Vt    = Vp + (size_t)BB * TT * DD;
  unsigned short* Obf   = Vt + (size_t)BB * TT * DD;

  const int M = BB * TT;  // 8192
  const int cvtBlocks = DD * DD / 8 / 256;  // 512

  convertT_k<<<cvtBlocks, 256, 0, stream>>>(Wq, WqT);
  convertT_k<<<cvtBlocks, 256, 0, stream>>>(Wk, WkT);
  convertT_k<<<cvtBlocks, 256, 0, stream>>>(Wv, WvT);
  convertT_k<<<cvtBlocks, 256, 0, stream>>>(Wo, WoT);

  gemm_k<1, 0><<<dim3(DD / 128, M / 128), 256, 0, stream>>>(query, WqT, bq, Qp, M, DD, DD);
  gemm_k<1, 0><<<dim3(DD / 128, M / 128), 256, 0, stream>>>(key,   WkT, bk, Kp, M, DD, DD);
  gemm_k<1, 0><<<dim3(DD / 128, M / 128), 256, 0, stream>>>(value, WvT, bv, Vp, M, DD, DD);

  transpose_v_k<<<BB * HH * (TT / 64), 256, 0, stream>>>(Vp, Vt);

  attn_k<<<BB * HH * (TT / 64), 256, 0, stream>>>(Qp, Kp, Vt, spat, edge, maskp, Obf);

  gemm_k<0, 1><<<dim3(DD / 128, M / 128), 256, 0, stream>>>(Obf, WoT, bo, out, M, DD, DD);
}